// Round 3
// baseline (803.014 us; speedup 1.0000x reference)
//
#include <hip/hip_runtime.h>

typedef unsigned short u16;
typedef __bf16 bf16_t;
typedef bf16_t bf16x8 __attribute__((ext_vector_type(8)));
typedef float f32x4 __attribute__((ext_vector_type(4)));

#define D_MODEL 2048
#define SEQ     2048
#define NHEAD   16
#define HDIM    128
#define IDIM    8192
#define QKV_LD  6144

// ---------- helpers ----------
__device__ __forceinline__ u16 f2bf(float f) {
    unsigned u = __float_as_uint(f);
    u += 0x7fffu + ((u >> 16) & 1u);           // RNE
    return (u16)(u >> 16);
}
__device__ __forceinline__ float bf2f(u16 u) {
    return __uint_as_float(((unsigned)u) << 16);
}
__device__ __forceinline__ void gload16(const void* g, void* l) {
    __builtin_amdgcn_global_load_lds(
        (const __attribute__((address_space(1))) unsigned int*)g,
        (__attribute__((address_space(3))) unsigned int*)l, 16, 0, 0);
}
#define MFMA16(a, b, c) __builtin_amdgcn_mfma_f32_16x16x32_bf16((a), (b), (c), 0, 0, 0)
#define VMCNT(n) asm volatile("s_waitcnt vmcnt(" #n ")" ::: "memory")
#define SBAR() do { __builtin_amdgcn_sched_barrier(0); __builtin_amdgcn_s_barrier(); __builtin_amdgcn_sched_barrier(0); } while (0)

// ---------- RMSNorm: fp32 in -> bf16 out ----------
__global__ __launch_bounds__(256) void rmsnorm_kernel(
    const float* __restrict__ x, const float* __restrict__ w, u16* __restrict__ out)
{
    int row = blockIdx.x, t = threadIdx.x;
    const float4* xr = (const float4*)(x + (size_t)row * D_MODEL);
    float4 a = xr[t * 2], b = xr[t * 2 + 1];
    float ss = a.x*a.x + a.y*a.y + a.z*a.z + a.w*a.w
             + b.x*b.x + b.y*b.y + b.z*b.z + b.w*b.w;
#pragma unroll
    for (int off = 32; off > 0; off >>= 1) ss += __shfl_down(ss, off, 64);
    __shared__ float red[4];
    __shared__ float sinv;
    if ((t & 63) == 0) red[t >> 6] = ss;
    __syncthreads();
    if (t == 0) sinv = rsqrtf((red[0] + red[1] + red[2] + red[3]) * (1.0f / D_MODEL) + 1e-5f);
    __syncthreads();
    float inv = sinv;
    const float4* w4 = (const float4*)w;
    float4 wa = w4[t * 2], wb = w4[t * 2 + 1];
    u16* o = out + (size_t)row * D_MODEL + t * 8;
    o[0] = f2bf(a.x * inv * wa.x); o[1] = f2bf(a.y * inv * wa.y);
    o[2] = f2bf(a.z * inv * wa.z); o[3] = f2bf(a.w * inv * wa.w);
    o[4] = f2bf(b.x * inv * wb.x); o[5] = f2bf(b.y * inv * wb.y);
    o[6] = f2bf(b.z * inv * wb.z); o[7] = f2bf(b.w * inv * wb.w);
}

// ---------- transpose + fp32->bf16 : src[R][C] -> dst[C][R] ----------
__global__ __launch_bounds__(256) void tcvt_kernel(
    const float* __restrict__ src, u16* __restrict__ dst, int R, int C)
{
    __shared__ float tile[32][33];
    int tx = threadIdx.x & 31, ty = threadIdx.x >> 5;
    int c = blockIdx.x * 32 + tx;
    int rb = blockIdx.y * 32;
#pragma unroll
    for (int i = 0; i < 32; i += 8)
        tile[ty + i][tx] = src[(size_t)(rb + ty + i) * C + c];
    __syncthreads();
    int dr = blockIdx.x * 32 + ty;
    int dc = rb + tx;
#pragma unroll
    for (int i = 0; i < 32; i += 8)
        dst[(size_t)(dr + i) * R + dc] = f2bf(tile[tx][ty + i]);
}

// ---------- bf16 transpose : src[R][C] (row stride ld) -> dst[C][R] ----------
__global__ __launch_bounds__(256) void tbf16_kernel(
    const u16* __restrict__ src, u16* __restrict__ dst, int R, int C, int ld)
{
    __shared__ u16 tile[32][34];
    int tx = threadIdx.x & 31, ty = threadIdx.x >> 5;
    int c = blockIdx.x * 32 + tx;
    int rb = blockIdx.y * 32;
#pragma unroll
    for (int i = 0; i < 32; i += 8)
        tile[ty + i][tx] = src[(size_t)(rb + ty + i) * ld + c];
    __syncthreads();
    int dr = blockIdx.x * 32 + ty;
    int dc = rb + tx;
#pragma unroll
    for (int i = 0; i < 32; i += 8)
        dst[(size_t)(dr + i) * R + dc] = tile[tx][ty + i];
}

// ---------- RoPE in-place on fused qkv buffer (q at col 0, k at col 2048) ----------
__global__ __launch_bounds__(256) void rope_kernel(
    u16* __restrict__ qkv, const float* __restrict__ fc, const float* __restrict__ fs)
{
    int s = blockIdx.x, t = threadIdx.x;
    const float* cr = fc + (size_t)s * HDIM;
    const float* sr = fs + (size_t)s * HDIM;
#pragma unroll
    for (int p = 0; p < 4; p++) {
        int pi = p * 256 + t;
        int h = pi >> 6, d = pi & 63;
        size_t base = (size_t)s * QKV_LD + h * HDIM + d;
        float c1 = cr[d], s1 = sr[d], c2 = cr[d + 64], s2 = sr[d + 64];
        float q1 = bf2f(qkv[base]), q2 = bf2f(qkv[base + 64]);
        qkv[base]      = f2bf(q1 * c1 - q2 * s1);
        qkv[base + 64] = f2bf(q2 * c2 + q1 * s2);
        size_t kb = base + 2048;
        float k1 = bf2f(qkv[kb]), k2 = bf2f(qkv[kb + 64]);
        qkv[kb]      = f2bf(k1 * c1 - k2 * s1);
        qkv[kb + 64] = f2bf(k2 * c2 + k1 * s2);
    }
}

// ---------- legacy GEMM (kept for wo projection) ----------
template <int BM, int EPI>
__global__ __launch_bounds__(256, 3) void gemm_bt(
    const u16* __restrict__ A, const u16* __restrict__ Bt,
    const float* __restrict__ res, const u16* __restrict__ gate,
    float* __restrict__ outf, u16* __restrict__ outb,
    int M, int N, int K, int lda, int ldb)
{
    constexpr int WC = (BM == 128) ? 2 : 4;   // waves along N
    constexpr int MI = 4;                      // 16-row frags per wave
    constexpr int NJ = (BM == 128) ? 4 : 2;   // 16-col frags per wave
    constexpr int LA = BM / 64;                // A staging passes (64 rows each)
    __shared__ __align__(16) u16 lA[BM * 32];
    __shared__ __align__(16) u16 lB[128 * 32];
    int t = threadIdx.x;
    int wave = t >> 6, lane = t & 63, quad = lane >> 4, l16 = lane & 15;
    int wr = wave / WC, wc = wave % WC;
    int m0 = blockIdx.y * BM, n0 = blockIdx.x * 128;
    int mb = wr * (MI * 16), nb = wc * (NJ * 16);
    int koff = blockIdx.z * K;

    f32x4 acc[MI][NJ];
    const f32x4 fzero = {0.f, 0.f, 0.f, 0.f};
#pragma unroll
    for (int i = 0; i < MI; i++)
#pragma unroll
        for (int j = 0; j < NJ; j++) acc[i][j] = fzero;

    const u16* gA[LA]; u16* lAp[LA];
#pragma unroll
    for (int l = 0; l < LA; l++) {
        int row = l * 64 + (t >> 2);
        int gch = (t & 3) ^ ((row >> 1) & 3);
        gA[l] = A + (size_t)(m0 + row) * lda + koff + gch * 8;
        lAp[l] = &lA[(l * 256 + t) * 8];
    }
    const u16* gB[2]; u16* lBp[2];
#pragma unroll
    for (int l = 0; l < 2; l++) {
        int row = l * 64 + (t >> 2);
        int gch = (t & 3) ^ ((row >> 1) & 3);
        gB[l] = Bt + (size_t)(n0 + row) * ldb + koff + gch * 8;
        lBp[l] = &lB[(l * 256 + t) * 8];
    }
    int fslot = (quad ^ ((l16 >> 1) & 3)) * 8;   // frag-read swizzled chunk

    for (int k0 = 0; k0 < K; k0 += 32) {
#pragma unroll
        for (int l = 0; l < LA; l++) gload16(gA[l] + k0, lAp[l]);
        gload16(gB[0] + k0, lBp[0]);
        gload16(gB[1] + k0, lBp[1]);
        asm volatile("s_waitcnt vmcnt(0)" ::: "memory");
        __syncthreads();
        bf16x8 af[MI], bfv[NJ];
#pragma unroll
        for (int i = 0; i < MI; i++)
            af[i] = *(const bf16x8*)&lA[(mb + i * 16 + l16) * 32 + fslot];
#pragma unroll
        for (int j = 0; j < NJ; j++)
            bfv[j] = *(const bf16x8*)&lB[(nb + j * 16 + l16) * 32 + fslot];
#pragma unroll
        for (int i = 0; i < MI; i++)
#pragma unroll
            for (int j = 0; j < NJ; j++)
                acc[i][j] = MFMA16(af[i], bfv[j], acc[i][j]);
        __syncthreads();
    }

    float* po = (EPI == 3) ? outf + (size_t)blockIdx.z * M * N : outf;
#pragma unroll
    for (int i = 0; i < MI; i++)
#pragma unroll
        for (int j = 0; j < NJ; j++)
#pragma unroll
            for (int r = 0; r < 4; r++) {
                int m = m0 + mb + i * 16 + quad * 4 + r;
                int n = n0 + nb + j * 16 + l16;
                size_t idx = (size_t)m * N + n;
                float v = acc[i][j][r];
                if (EPI == 0) {
                    outb[idx] = f2bf(v);
                } else if (EPI == 1) {
                    outf[idx] = res[idx] + v;
                } else if (EPI == 2) {
                    float g = bf2f(gate[idx]);
                    outb[idx] = f2bf(g / (1.f + __expf(-g)) * v);
                } else {
                    po[idx] = v;
                }
            }
}

// ---------- 256x256 8-wave pipelined GEMM: C = A @ Bt^T ----------
// BK=64, double-buffered LDS (128 KB), tile-granular 2-phase pipeline:
//   iter t: issue ALL 8 segs of tile t+1 into buf 1-c, then vmcnt(8)
//   certifies exactly tile t's 8 oldest loads -> t+1's stay in flight
//   across the barrier (never drained mid-loop). Full-tile certification
//   is REQUIRED by the wave layout: every wave's B reads span all four
//   64-row B segments (wn covers rows 0-255), so half-tile certification
//   races (round-2 failure).
// LDS [row][64] with 16B-chunk XOR swizzle slot = chunk ^ (row&7), applied
// to the pre-swizzled global source (linear global_load_lds dest) and the
// same involution on ds_read -> 2-way conflict (free).
// EPI 0: bf16 store. EPI 2: bf16 silu(gate)*acc. EPI 3: f32 split-K partial.
template <int EPI>
__global__ __launch_bounds__(512, 2) void gemm256(
    const u16* __restrict__ A, const u16* __restrict__ Bt,
    const u16* __restrict__ gate, float* __restrict__ outf, u16* __restrict__ outb,
    int M, int N, int K, int lda, int ldb)
{
    __shared__ __align__(16) u16 sA[2][256 * 64];
    __shared__ __align__(16) u16 sB[2][256 * 64];
    int tid = threadIdx.x;
    int lane = tid & 63, quad = lane >> 4, l16 = lane & 15;
    int wave = tid >> 6, wm = wave >> 2, wn = wave & 3;
    int x8 = l16 & 7;

    // XCD-aware swizzle, m-grouped within XCD (share B panels in L2)
    int nbn = gridDim.x, nbm = gridDim.y;
    int nwg = nbn * nbm;                       // always a multiple of 8 here
    int nb = blockIdx.y * nbn + blockIdx.x;
    int q8 = nwg >> 3;
    int sw = (nb & 7) * q8 + (nb >> 3);
    int m0 = (sw % nbm) * 256, n0 = (sw / nbm) * 256;
    size_t koff = (size_t)blockIdx.z * K;

    // staging: 8 threads per 128B row; global chunk pre-swizzled by row&7
    int srow = tid >> 3, slot = tid & 7;
    const u16* gA[2][2]; const u16* gB[2][2];
#pragma unroll
    for (int h = 0; h < 2; h++)
#pragma unroll
        for (int l = 0; l < 2; l++) {
            int row = h * 128 + l * 64 + srow;
            int gch = slot ^ (row & 7);
            gA[h][l] = A + (size_t)(m0 + row) * lda + koff + gch * 8;
            gB[h][l] = Bt + (size_t)(n0 + row) * ldb + koff + gch * 8;
        }

    f32x4 acc[8][4];
    const f32x4 fzero = {0.f, 0.f, 0.f, 0.f};
#pragma unroll
    for (int i = 0; i < 8; i++)
#pragma unroll
        for (int j = 0; j < 4; j++) acc[i][j] = fzero;

#define ISSUE_TILE(KOFF, AD, BD)                                               \
    gload16(gA[0][0] + (KOFF), (AD) + tid * 8);                                \
    gload16(gA[0][1] + (KOFF), (AD) + 4096 + tid * 8);                         \
    gload16(gA[1][0] + (KOFF), (AD) + 8192 + tid * 8);                         \
    gload16(gA[1][1] + (KOFF), (AD) + 12288 + tid * 8);                        \
    gload16(gB[0][0] + (KOFF), (BD) + tid * 8);                                \
    gload16(gB[0][1] + (KOFF), (BD) + 4096 + tid * 8);                         \
    gload16(gB[1][0] + (KOFF), (BD) + 8192 + tid * 8);                         \
    gload16(gB[1][1] + (KOFF), (BD) + 12288 + tid * 8);

#define READ_A(MH)                                                             \
    _Pragma("unroll")                                                          \
    for (int mi = 0; mi < 4; mi++)                                             \
        _Pragma("unroll")                                                      \
        for (int kk = 0; kk < 2; kk++)                                         \
            af[mi][kk] = *(const bf16x8*)&sac[(wm * 128 + (MH) * 64 + mi * 16 + l16) * 64 \
                                              + (((kk * 4 + quad) ^ x8) * 8)];
#define READ_B(BF, NH)                                                         \
    _Pragma("unroll")                                                          \
    for (int nj = 0; nj < 2; nj++)                                             \
        _Pragma("unroll")                                                      \
        for (int kk = 0; kk < 2; kk++)                                         \
            BF[nj][kk] = *(const bf16x8*)&sbc[(wn * 64 + (NH) * 32 + nj * 16 + l16) * 64 \
                                              + (((kk * 4 + quad) ^ x8) * 8)];
#define QUAD_MFMA(BF, IOFF, JOFF)                                              \
    __builtin_amdgcn_s_setprio(1);                                             \
    _Pragma("unroll")                                                          \
    for (int kk = 0; kk < 2; kk++)                                             \
        _Pragma("unroll")                                                      \
        for (int mi = 0; mi < 4; mi++)                                         \
            _Pragma("unroll")                                                  \
            for (int nj = 0; nj < 2; nj++)                                     \
                acc[(IOFF) + mi][(JOFF) + nj] =                                \
                    MFMA16(af[mi][kk], BF[nj][kk], acc[(IOFF) + mi][(JOFF) + nj]); \
    __builtin_amdgcn_s_setprio(0);

    // prologue: tile 0 -> buf 0, fully drained
    ISSUE_TILE(0, sA[0], sB[0])
    VMCNT(0);
    SBAR();

    int nk = K >> 6;
    for (int t = 0; t < nk; ++t) {
        int c = t & 1;
        const u16* sac = sA[c]; const u16* sbc = sB[c];
        bool pf = (t + 1 < nk);

        // issue tile t+1 into buf 1-c (free since end-of-(t-1) barrier),
        // then certify tile t: vmcnt(8) leaves exactly t+1's loads in flight
        if (pf) {
            int kn = (t + 1) << 6;
            u16* sad = sA[c ^ 1]; u16* sbd = sB[c ^ 1];
            ISSUE_TILE(kn, sad, sbd)
            VMCNT(8);
        } else {
            VMCNT(0);
        }
        SBAR();                       // tile t visible to all waves

        // compute tile t (64 MFMA/wave), no intra-tile barriers
        bf16x8 af[4][2], bf0[2][2], bf1[2][2];
        READ_A(0)
        READ_B(bf0, 0)
        READ_B(bf1, 1)
        QUAD_MFMA(bf0, 0, 0)
        QUAD_MFMA(bf1, 0, 2)
        READ_A(1)
        QUAD_MFMA(bf0, 4, 0)
        QUAD_MFMA(bf1, 4, 2)

        asm volatile("s_waitcnt lgkmcnt(0)" ::: "memory");
        SBAR();                       // all reads of buf c done -> reusable
    }
#undef ISSUE_TILE
#undef READ_A
#undef READ_B
#undef QUAD_MFMA

    float* po = (EPI == 3) ? outf + (size_t)blockIdx.z * M * N : outf;
#pragma unroll
    for (int i = 0; i < 8; i++)
#pragma unroll
        for (int j = 0; j < 4; j++)
#pragma unroll
            for (int r = 0; r < 4; r++) {
                int m = m0 + wm * 128 + (i >> 2) * 64 + (i & 3) * 16 + quad * 4 + r;
                int n = n0 + wn * 64 + (j >> 1) * 32 + (j & 1) * 16 + l16;
                size_t idx = (size_t)m * N + n;
                float v = acc[i][j][r];
                if (EPI == 0) {
                    outb[idx] = f2bf(v);
                } else if (EPI == 2) {
                    float g = bf2f(gate[idx]);
                    outb[idx] = f2bf(g / (1.f + __expf(-g)) * v);
                } else {
                    po[idx] = v;
                }
            }
}

// ---------- split-K reduce: out = x1 + sum_z part[z] ----------
__global__ __launch_bounds__(256) void reduce4_kernel(
    const float* __restrict__ x1, const float* __restrict__ part, float* __restrict__ out)
{
    size_t i = (size_t)blockIdx.x * 256 + threadIdx.x;   // float4 index
    float4 a = ((const float4*)x1)[i];
#pragma unroll
    for (int z = 0; z < 4; z++) {
        float4 pv = ((const float4*)(part + (size_t)z * SEQ * D_MODEL))[i];
        a.x += pv.x; a.y += pv.y; a.z += pv.z; a.w += pv.w;
    }
    ((float4*)out)[i] = a;
}

// ---------- flash attention v2: one block per (q-tile 128, head) ----------
__global__ __launch_bounds__(256, 1) void attn_kernel(
    const u16* __restrict__ q, const u16* __restrict__ k,
    const u16* __restrict__ vt, u16* __restrict__ ctx)
{
    __shared__ __align__(16) u16 sK[2][128 * 128];   // 2 x 32 KB, K tiles
    __shared__ __align__(16) u16 sV[128 * 128];      // 32 KB, V^T tile [d][k]
    __shared__ __align__(16) u16 sP[4][16 * 32 * 8]; // 8 KB/wave P scratch

    int t = threadIdx.x;
    int wave = t >> 6, lane = t & 63, quad = lane >> 4, l16 = lane & 15;
    int h = blockIdx.y, qt = blockIdx.x;
    int q0 = qt * 128;
    int srow = t >> 4, schunk = t & 15;           // staging: 16 lanes per 256B row

    // ---- prologue: stage Q -> sK[1], K(0) -> sK[0]
#pragma unroll
    for (int p = 0; p < 8; p++) {
        int r = p * 16 + srow;
        int gc = schunk ^ (r & 7);
        gload16(q + (size_t)(q0 + r) * QKV_LD + h * HDIM + gc * 8, &sK[1][p * 2048 + t * 8]);
    }
#pragma unroll
    for (int p = 0; p < 8; p++) {
        int r = p * 16 + srow;
        int gc = schunk ^ (r & 7);
        gload16(k + (size_t)r * QKV_LD + h * HDIM + gc * 8, &sK[0][p * 2048 + t * 8]);
    }
    asm volatile("s_waitcnt vmcnt(0)" ::: "memory");
    __builtin_amdgcn_s_barrier();
    __builtin_amdgcn_sched_barrier(0);

    // Q fragments -> registers
    bf16x8 qa[2][4];
#pragma unroll
    for (int i = 0; i < 2; i++) {
        int row = wave * 32 + i * 16 + l16;
#pragma unroll
        for (int kk = 0; kk < 4; kk++)
            qa[i][kk] = *(const bf16x8*)&sK[1][row * 128 + (((kk * 4 + quad) ^ (row & 7)) * 8)];
    }
    asm volatile("s_waitcnt lgkmcnt(0)" ::: "memory");
    __builtin_amdgcn_sched_barrier(0);
    __builtin_amdgcn_s_barrier();          // sK[1] now free for K(1) DMA
    __builtin_amdgcn_sched_barrier(0);

    const float scale = 0.08838834764831845f;  // 1/sqrt(128)
    float m_r[2][4], l_r[2][4];
#pragma unroll
    for (int i = 0; i < 2; i++)
#pragma unroll
        for (int r = 0; r < 4; r++) { m_r[i][r] = -3e38f; l_r[i][r] = 0.f; }
    const f32x4 fzero = {0.f, 0.f, 0.f, 0.f};
    f32x4 o[2][8];
#pragma unroll
    for (int i = 0; i < 2; i++)
#pragma unroll
        for (int j = 0; j < 8; j++) o[i][j] = fzero;
    u16* sPw = sP[wave];

    for (int kt = 0; kt <= qt; kt++) {
        int c = kt & 1;
        int k0 = kt * 128;

        // issue V(kt) -> sV
#pragma unroll
        for (int p = 0; p < 8; p++) {
            int r = p * 16 + srow;
            int gc = schunk ^ (r & 7);
            gload16(vt + (size_t)(h * HDIM + r) * SEQ + k0 + gc * 8, &sV[p * 2048 + t * 8]);
        }
        // issue K(kt+1) -> sK[1-c], then wait only for own K(kt)
        if (kt < qt) {
            int k1 = k0 + 128;
#pragma unroll
            for (int p = 0; p < 8; p++) {
                int r = p * 16 + srow;
                int gc = schunk ^ (r & 7);
                gload16(k + (size_t)(k1 + r) * QKV_LD + h * HDIM + gc * 8,
                        &sK[1 - c][p * 2048 + t * 8]);
            }
            asm volatile("s_waitcnt vmcnt(16)" ::: "memory");  // leaves V + nextK in flight
        } else {
            asm volatile("s_waitcnt vmcnt(8)" ::: "memory");   // leaves V in flight
        }
        __builtin_amdgcn_sched_barrier(0);
        __builtin_amdgcn_s_barrier();                          // B1: K(kt) visible
        __builtin_amdgcn_sched_barrier(0);

        // ---- QK^T
        f32x4 sc[2][8];
#pragma unroll
        for (int i = 0; i < 2; i++)
#pragma unroll
            for (int j = 0; j < 8; j++) sc[i][j] = fzero;
        const u16* sKc = sK[c];
#pragma unroll
        for (int kk = 0; kk < 4; kk++) {
            bf16x8 kf[8];
#pragma unroll
            for (int j = 0; j < 8; j++)
                kf[j] = *(const bf16x8*)&sKc[(j * 16 + l16) * 128 +
                                             (((kk * 4 + quad) ^ (l16 & 7)) * 8)];
#pragma unroll
            for (int i = 0; i < 2; i++)
#pragma unroll
                for (int j = 0; j < 8; j++)
                    sc[i][j] = MFMA16(qa[i][kk], kf[j], sc[i][j]);
        }

        // scale, causal mask only on the diagonal tile
#pragma unroll
        for (int i = 0; i < 2; i++)
#pragma unroll
            for (int j = 0; j < 8; j++) sc[i][j] = sc[i][j] * scale;
        if (kt == qt) {
#pragma unroll
            for (int i = 0; i < 2; i++)
#pragma unroll
                for (int j = 0; j < 8; j++) {
                    int col = j * 16 + l16;
#pragma unroll
                    for (int r = 0; r < 4; r++) {
                        int row = wave * 32 + i * 16 + quad * 4 + r;
                        if (col > row) sc[i][j][r] = -3e38f;
                    }
                }
        }

        // ---- online softmax, wave-local
#pragma unroll
        for (int i = 0; i < 2; i++)
#pragma unroll
            for (int r = 0; r < 4; r++) {
                float mx = sc[i][0][r];
#pragma unroll
                for (int j = 1; j < 8; j++) mx = fmaxf(mx, sc[i][j][r]);
#pragma unroll
                for (int d = 1; d < 16; d <<= 1) mx = fmaxf(mx, __shfl_xor(mx, d, 64));
                float mo = m_r[i][r];
                float mn = fmaxf(mo, mx);
                float al = __expf(mo - mn);
                m_r[i][r] = mn;
                float s = 0.f;
#pragma unroll
                for (int j = 0; j < 8; j++) {
                    float pv = __expf(sc[i][j][r] - mn);
                    sc[i][j][r] = pv;
                    s += pv;
                }
#pragma unroll
                for (int d = 1; d < 16; d <<= 1) s += __shfl_xor(s, d, 64);
                l_r[i][r] = al * l_r[i][r] + s;
#pragma unroll
                for (int j = 0; j < 8; j++) o[i][j][r] *= al;
                int rl = i * 16 + quad * 4 + r;
#pragma unroll
                for (int j = 0; j < 8; j++) {
                    int col = j * 16 + l16;
                    sPw[(col >> 3) * 256 + rl * 8 + (col & 7)] = f2bf(sc[i][j][r]);
                }
            }

        // wait own V(kt) + own P writes; keep nextK in flight
        if (kt < qt) {
            asm volatile("s_waitcnt vmcnt(8) lgkmcnt(0)" ::: "memory");
        } else {
            asm volatile("s_waitcnt vmcnt(0) lgkmcnt(0)" ::: "memory");
        }
        __builtin_amdgcn_sched_barrier(0);
        __builtin_amdgcn_s_barrier();                          // B2: V(kt) visible
        __builtin_amdgcn_sched_barrier(0);

        // ---- O += P @ V^T-tile
#pragma unroll
        for (int kk = 0; kk < 4; kk++) {
            bf16x8 pa[2], vf[8];
#pragma unroll
            for (int i = 0; i < 2; i++)
                pa[i] = *(const bf16x8*)&sPw[(kk * 4 + quad) * 256 + (i * 16 + l16) * 8];
#pragma unroll
            for (int j = 0; j < 8; j++)
                vf[j] = *(const bf16x8*)&sV[(j * 16 + l16) * 128 +
                                            (((kk * 4 + quad) ^ (l16 & 7)) * 8)];
#pragma unroll
            for (int i = 0; i < 2; i++)
#pragma unroll
                for (int j = 0; j < 8; j++)
                    o[i][j] = MFMA16(pa[i], vf[j], o[i][j]);
        }
        asm volatile("s_waitcnt lgkmcnt(0)" ::: "memory");
        __builtin_amdgcn_sched_barrier(0);
        __builtin_amdgcn_s_barrier();                          // B3: sV / sK[c] free
        __builtin_amdgcn_sched_barrier(0);
    }

    // ---- epilogue
#pragma unroll
    for (int i = 0; i < 2; i++)
#pragma unroll
        for (int r = 0; r < 4; r++) {
            int row = wave * 32 + i * 16 + quad * 4 + r;
            float inv = 1.f / l_r[i][r];
#pragma unroll
            for (int j = 0; j < 8; j++) {
                int n = h * HDIM + j * 16 + l16;
                ctx[(size_t)(q0 + row) * D_MODEL + n] = f2bf(o[i][j][r] * inv);
            }
        }
}

// ---------- host launch ----------
extern "C" void kernel_launch(void* const* d_in, const int* in_sizes, int n_in,
                              void* d_out, int out_size, void* d_ws, size_t ws_size,
                              hipStream_t stream)
{
    const float* x    = (const float*)d_in[0];
    const float* fcos = (const float*)d_in[2];
    const float* fsin = (const float*)d_in[3];
    const float* wq   = (const float*)d_in[4];
    const float* wk   = (const float*)d_in[5];
    const float* wv   = (const float*)d_in[6];
    const float* wo   = (const float*)d_in[7];
    const float* w1   = (const float*)d_in[8];
    const float* w2   = (const float*)d_in[9];
    const float* w3   = (const float*)d_in[10];
    const float* anw  = (const float*)d_in[11];
    const float* fnw  = (const float*)d_in[12];
    float* out = (float*)d_out;

    const size_t MB = 1024 * 1024;
    char* base = (char*)d_ws;
    u16*   qkvT = (u16*)  (base + 0);          // 24 MB  [6144][2048] bf16
    u16*   woT  = (u16*)  (base + 24 * MB);    //  8 MB
    u16*   w1T  = (u16*)  (base + 32 * MB);    // 32 MB
    u16*   w3T  = (u16*)  (base + 64 * MB);    // 32 MB
    u16*   w2T  = (u16*)  (base + 96 * MB);    // 32 MB
    u16*   nx   = (u16*)  (base + 128 * MB);   //  8 MB
    u16*   qkv  = (u16*)  (base + 136 * MB);   // 24 MB  [2048][6144] bf16
    u16*   vtb  = (u16*)  (base + 160 * MB);   //  8 MB
    u16*   ctxb = (u16*)  (base + 168 * MB);   //  8 MB
    float* x1   = (float*)(base + 176 * MB);   // 16 MB
    u16*   nx2  = (u16*)  (base + 192 * MB);   //  8 MB
    u16*   h1b  = (u16*)  (base + 200 * MB);   // 32 MB
    u16*   hb   = (u16*)  (base + 232 * MB);   // 32 MB -> total 264 MB
    // split-K partials (64 MB f32) alias [0,64) MB — dead before w2 GEMM.
    float* part = (float*)(base + 0);

    dim3 blk(256);
    dim3 blk512(512);

    rmsnorm_kernel<<<SEQ, blk, 0, stream>>>(x, anw, nx);
    tcvt_kernel<<<dim3(64, 64),  blk, 0, stream>>>(wq, qkvT,                       D_MODEL, D_MODEL);
    tcvt_kernel<<<dim3(64, 64),  blk, 0, stream>>>(wk, qkvT + 2048 * 2048,         D_MODEL, D_MODEL);
    tcvt_kernel<<<dim3(64, 64),  blk, 0, stream>>>(wv, qkvT + (size_t)4096 * 2048, D_MODEL, D_MODEL);
    tcvt_kernel<<<dim3(64, 64),  blk, 0, stream>>>(wo, woT, D_MODEL, D_MODEL);
    tcvt_kernel<<<dim3(256, 64), blk, 0, stream>>>(w1, w1T, D_MODEL, IDIM);
    tcvt_kernel<<<dim3(256, 64), blk, 0, stream>>>(w3, w3T, D_MODEL, IDIM);
    tcvt_kernel<<<dim3(64, 256), blk, 0, stream>>>(w2, w2T, IDIM, D_MODEL);

    // fused QKV projection: [2048][6144]  (24x8 = 192 blocks)
    gemm256<0><<<dim3(24, 8), blk512, 0, stream>>>(
        nx, qkvT, nullptr, nullptr, qkv, SEQ, QKV_LD, D_MODEL, D_MODEL, D_MODEL);

    rope_kernel<<<SEQ, blk, 0, stream>>>(qkv, fcos, fsin);
    tbf16_kernel<<<dim3(64, 64), blk, 0, stream>>>(qkv + 4096, vtb, SEQ, D_MODEL, QKV_LD);

    attn_kernel<<<dim3(16, 16), blk, 0, stream>>>(qkv, qkv + 2048, vtb, ctxb);

    // wo projection + residual (BM=64 -> 512 blocks, legacy kernel)
    gemm_bt<64, 1><<<dim3(16, 32), blk, 0, stream>>>(
        ctxb, woT, x, nullptr, x1, nullptr, SEQ, D_MODEL, D_MODEL, D_MODEL, D_MODEL);

    rmsnorm_kernel<<<SEQ, blk, 0, stream>>>(x1, fnw, nx2);

    // FFN: h1 = nx2@w1T ; h = silu(h1) * (nx2@w3T)   (32x8 = 256 blocks each)
    gemm256<0><<<dim3(32, 8), blk512, 0, stream>>>(
        nx2, w1T, nullptr, nullptr, h1b, SEQ, IDIM, D_MODEL, D_MODEL, D_MODEL);
    gemm256<2><<<dim3(32, 8), blk512, 0, stream>>>(
        nx2, w3T, h1b, nullptr, hb, SEQ, IDIM, D_MODEL, D_MODEL, D_MODEL);

    // w2 GEMM split-K x4 (8x8x4 = 256 blocks), then reduce + residual
    gemm256<3><<<dim3(8, 8, 4), blk512, 0, stream>>>(
        hb, w2T, nullptr, part, nullptr, SEQ, D_MODEL, D_MODEL, IDIM, IDIM);
    reduce4_kernel<<<dim3(4096), blk, 0, stream>>>(x1, part, out);
}